// Round 10
// baseline (2384.352 us; speedup 1.0000x reference)
//
#include <hip/hip_runtime.h>

#define T_STEPS 128
#define BATCH   128
#define DX      1024
#define DH      1024
#define BDH     (BATCH * DH)   // 131072
#define BDX     (BATCH * DX)
#define PLW     40             // pl row stride (words)

typedef __attribute__((ext_vector_type(8)))  short short8;
typedef __attribute__((ext_vector_type(16))) float f32x16;
typedef __attribute__((ext_vector_type(4)))  float f32x4v;
typedef __attribute__((ext_vector_type(2)))  float f32x2;
typedef __attribute__((ext_vector_type(4)))  unsigned u32x4;
typedef __attribute__((ext_vector_type(2)))  _Float16 f16x2;

static __device__ __forceinline__ unsigned short f2bf(float f) {
    union { float f; unsigned u; } v; v.f = f;
    unsigned r = v.u + 0x7fffu + ((v.u >> 16) & 1u);   // RNE
    return (unsigned short)(r >> 16);
}
static __device__ __forceinline__ short8 pack_bf16x8(f32x4v lo, f32x4v hi) {
    union { unsigned short u[8]; short8 v; } pk;
    pk.u[0]=f2bf(lo[0]); pk.u[1]=f2bf(lo[1]); pk.u[2]=f2bf(lo[2]); pk.u[3]=f2bf(lo[3]);
    pk.u[4]=f2bf(hi[0]); pk.u[5]=f2bf(hi[1]); pk.u[6]=f2bf(hi[2]); pk.u[7]=f2bf(hi[3]);
    return pk.v;
}
static __device__ __forceinline__ float sigf(float x) {
    float u = __expf(-fabsf(x));
    float b = 1.0f / (1.0f + u);
    return x >= 0.0f ? b : 1.0f - b;
}
static __device__ __forceinline__ float tanhfast(float x) {
    float u = __expf(-2.0f * fabsf(x));
    float r = (1.0f - u) / (1.0f + u);
    return x >= 0.0f ? r : -r;
}

// ---------------- prep kernels ----------------

__global__ __launch_bounds__(256) void prep_x(const float* __restrict__ x,
                                              unsigned short* __restrict__ Xb) {
    const size_t i8 = ((size_t)blockIdx.x * 256 + threadIdx.x) * 8;
    f32x4v lo = __builtin_nontemporal_load((const f32x4v*)(x + i8));
    f32x4v hi = __builtin_nontemporal_load((const f32x4v*)(x + i8 + 4));
    short8 v = pack_bf16x8(lo, hi);
    __builtin_nontemporal_store(v, (short8*)(Xb + i8));
}

// TM = tanh(memories), f16
__global__ __launch_bounds__(256) void prep_tm(const float* __restrict__ mem,
                                               _Float16* __restrict__ TM) {
    const size_t i8 = ((size_t)blockIdx.x * 256 + threadIdx.x) * 8;
    f32x4v lo = __builtin_nontemporal_load((const f32x4v*)(mem + i8));
    f32x4v hi = __builtin_nontemporal_load((const f32x4v*)(mem + i8 + 4));
    union { _Float16 h[8]; u32x4 q; } V;
    #pragma unroll
    for (int j = 0; j < 4; ++j) V.h[j]     = (_Float16)tanhfast(lo[j]);
    #pragma unroll
    for (int j = 0; j < 4; ++j) V.h[4 + j] = (_Float16)tanhfast(hi[j]);
    __builtin_nontemporal_store(V.q, (u32x4*)(TM + i8));
}

__global__ __launch_bounds__(256) void init_seed(const float* __restrict__ h0,
                                                 unsigned short* __restrict__ hseq,
                                                 unsigned* __restrict__ gflag) {
    const int i = blockIdx.x * 256 + threadIdx.x;
    if (i < BDH) hseq[i] = f2bf(h0[i]);
    if (blockIdx.x < 2) gflag[blockIdx.x * 256 + threadIdx.x] = 0;
}

// ---------------- Gx prepass (R6 geometry, W staged from f32) ----------------
// Grid 512: c = bid&7 (XCD chunk -> timesteps c*16..+16; per-XCD x slice 4MB
// bf16, L2-resident), jp = bid>>3 (0..63: 64 perm rows). Stage 128KB W slab
// ONCE from Wx f32 (NT), loop 16 timesteps: M=128 x N=64, K=1024; x A-tile
// read once per mt shared by both N-tiles. Gx f16 out (bias folded, NT).
__global__ __launch_bounds__(256, 1) void gx_prepass4(
    const unsigned short* __restrict__ Xb, const float* __restrict__ Wx,
    const float* __restrict__ bx, const float* __restrict__ bh,
    _Float16* __restrict__ Gx)
{
    extern __shared__ char sm[];                  // [0,128K): W slab; then pl16
    _Float16* pl16 = (_Float16*)(sm + 131072);    // [128][72]

    const int bid = blockIdx.x;
    const int c  = bid & 7;
    const int jp = bid >> 3;                      // 0..63
    const int tid = threadIdx.x;

    {   // stage W slab: 64 perm rows [jp*64,+64), f32->bf16, swizzled
        const int row = tid >> 2;                 // 0..63
        const int chunk = tid & 3;                // K quarter (256 elems)
        const int prow = jp * 64 + row;
        const int srow = ((prow >> 3) & 3) * 1024 + 1024   // gate g+1
                       + (prow >> 5) * 8 + (prow & 7);
        const int sw = (row & 7) << 4;
        const float* W = Wx + (size_t)srow * DX + chunk * 256;
        char* dst = sm + row * 2048;
        #pragma unroll
        for (int it = 0; it < 32; ++it) {
            f32x4v lo = __builtin_nontemporal_load((const f32x4v*)(W + it * 8));
            f32x4v hi = __builtin_nontemporal_load((const f32x4v*)(W + it * 8 + 4));
            short8 v = pack_bf16x8(lo, hi);
            *(short8*)(dst + (((chunk * 256 + it * 8) * 2) ^ sw)) = v;
        }
    }

    const int rrow = tid >> 1;
    const int jjb  = (tid & 1) * 4;
    float bias_f[2][16];
    #pragma unroll
    for (int jsl = 0; jsl < 2; ++jsl)
        #pragma unroll
        for (int q = 0; q < 4; ++q)
            #pragma unroll
            for (int g = 0; g < 4; ++g) {
                const int srow = (g + 1) * 1024 + (jp * 2 + jsl) * 8 + (jjb + q);
                bias_f[jsl][q * 4 + g] = bx[srow] + bh[srow];
            }

    const int wave = tid >> 6, lane = tid & 63;
    const int k8 = (lane >> 5) * 8;
    const char* wrow0 = sm + (lane & 31) * 2048;
    const char* wrow1 = wrow0 + 32 * 2048;
    const int sw2 = ((lane & 31) & 7) << 4;
    __syncthreads();

    for (int i = 0; i < 16; ++i) {
        const int mt = c * 16 + i;                // timestep
        const int arow = mt * 128 + wave * 32 + (lane & 31);
        f32x16 a00 = {}, a01 = {}, a10 = {}, a11 = {};

        const unsigned short* xp = Xb + (size_t)arow * 1024 + k8;
        #pragma unroll 8
        for (int ks = 0; ks < 64; ++ks) {
            short8 a  = *(const short8*)(xp + ks * 16);      // cached: L2-shared
            short8 b0 = *(const short8*)(wrow0 + ((ks * 32 + k8 * 2) ^ sw2));
            short8 b1 = *(const short8*)(wrow1 + ((ks * 32 + k8 * 2) ^ sw2));
            if (ks & 1) {
                a01 = __builtin_amdgcn_mfma_f32_32x32x16_bf16(a, b0, a01, 0, 0, 0);
                a11 = __builtin_amdgcn_mfma_f32_32x32x16_bf16(a, b1, a11, 0, 0, 0);
            } else {
                a00 = __builtin_amdgcn_mfma_f32_32x32x16_bf16(a, b0, a00, 0, 0, 0);
                a10 = __builtin_amdgcn_mfma_f32_32x32x16_bf16(a, b1, a10, 0, 0, 0);
            }
        }
        f32x16 r0 = a00 + a01;
        f32x16 r1 = a10 + a11;

        #pragma unroll
        for (int ii = 0; ii < 16; ++ii) {
            const int rowc = (ii & 3) + 8 * (ii >> 2) + 4 * (lane >> 5);
            pl16[(wave * 32 + rowc) * 72 + (lane & 31)]      = (_Float16)r0[ii];
            pl16[(wave * 32 + rowc) * 72 + 32 + (lane & 31)] = (_Float16)r1[ii];
        }
        __syncthreads();   // pl written

        #pragma unroll
        for (int jsl = 0; jsl < 2; ++jsl) {
            union { _Float16 h[16]; u32x4 q[2]; } V;
            #pragma unroll
            for (int q = 0; q < 4; ++q)
                #pragma unroll
                for (int g = 0; g < 4; ++g)
                    V.h[q * 4 + g] = (_Float16)(
                        (float)pl16[rrow * 72 + jsl * 32 + g * 8 + (jjb + q)]
                        + bias_f[jsl][q * 4 + g]);
            _Float16* dst = Gx + ((size_t)(mt * 128 + rrow) * 4096
                                  + (jp * 2 + jsl) * 32 + jjb * 4);
            __builtin_nontemporal_store(V.q[0], (u32x4*)dst);
            __builtin_nontemporal_store(V.q[1], (u32x4*)(dst + 8));
        }
        __syncthreads();   // pl consumed before next mt overwrites
    }
}

// ---------------- persistent h-recurrence kernel (1 barrier/step) ----------------
// 256 WGs (1/CU). bhh-clustered XCD map: js=(bid>>3)*4+(bid&3), bhh=(bid>>2)&1.
// WG: 64 batch rows x 8 j-cols. Waves: mh=wave>>1 (M-subtile), kh=wave&1
// (K=512 half). Wh B-frags in 128 VGPRs. pl DOUBLE-buffered -> single
// __syncthreads per step. Each wave polls only ITS 64 producers (the WGs
// owning h-columns [kh*512,+512)). Flag set by the LAST wave (LDS hdone
// atomic; every wave incs after its own vmcnt(0) drain of the sc1 h-store).
__global__ __launch_bounds__(256, 1) void eplstm_h(
    const _Float16* __restrict__ Gx,  const _Float16* __restrict__ TM,
    const float* __restrict__ Wh,     const float* __restrict__ c0,
    unsigned short* __restrict__ hseq, float* __restrict__ out,
    unsigned* __restrict__ gflag)
{
    __shared__ float pl[2][4 * 32 * PLW];          // 2 x 20 KiB
    __shared__ unsigned hdone;

    const int bid = blockIdx.x;
    const int js  = (bid >> 3) * 4 + (bid & 3);    // 0..127
    const int bhh = (bid >> 2) & 1;
    const int tid = threadIdx.x;

    const int wave = tid >> 6, lane = tid & 63;
    const int mh = wave >> 1, kh = wave & 1;
    const int arow = bhh * 64 + mh * 32 + (lane & 31);
    const int k8 = (lane >> 5) * 8;
    const int p = lane & 31;
    const int word = (p & 7) * 4 + (p >> 3);       // jj*4 + g
    // wave kh consumes h cols [kh*512,+512) -> producers js' in [kh*64,+64)
    const unsigned* fw = gflag + bhh * 128 + kh * 64;

    // ---- stage this lane's 32 Wh B-fragments into registers (one-time) ----
    short8 breg[32];
    {
        const int r = lane & 31;
        const int g = r >> 3, jj = r & 7;
        const float* Wrow = Wh + (size_t)((g + 1) * 1024 + js * 8 + jj) * 1024
                          + kh * 512 + k8;
        #pragma unroll
        for (int ks = 0; ks < 32; ++ks) {
            f32x4v lo = *(const f32x4v*)(Wrow + ks * 16);
            f32x4v hi = *(const f32x4v*)(Wrow + ks * 16 + 4);
            breg[ks] = pack_bf16x8(lo, hi);
        }
    }

    // epilogue constants (2 outputs/thread)
    const int e0 = tid * 2;
    const int row_e = e0 >> 3;                     // 0..63
    const int jj0 = e0 & 7;                        // even
    const int brow = bhh * 64 + row_e;
    const size_t obase = (size_t)brow * DH + js * 8 + jj0;
    const int mh_e = row_e >> 5, r_e = row_e & 31;
    float2 creg = *(const float2*)(c0 + obase);

    if (tid == 0) hdone = 0;
    __syncthreads();

    for (int t = 0; t < T_STEPS; ++t) {
        // prefetch h-independent operands BEFORE the wait (NT: single-touch)
        u32x4 gxv = __builtin_nontemporal_load(
            (const u32x4*)(Gx + ((size_t)(t * BATCH + brow) * 4096 + js * 32 + jj0 * 4)));
        f16x2 tm2 = __builtin_nontemporal_load(
            (const f16x2*)(TM + (size_t)t * BDH + obase));

        if (t > 0) {
            for (;;) {       // every wave polls its own 64 producers
                unsigned f = __hip_atomic_load(&fw[lane], __ATOMIC_RELAXED,
                                               __HIP_MEMORY_SCOPE_AGENT);
                if (__all(f >= (unsigned)t)) break;
                __builtin_amdgcn_s_sleep(1);
            }
        }

        const unsigned short* hp = hseq + (size_t)t * BDH + (size_t)arow * DH + kh * 512 + k8;
        f32x16 a0 = {}, a1 = {};
        #pragma unroll
        for (int ks = 0; ks < 32; ++ks) {
            short8 a = *(const short8*)(hp + ks * 16);
            if (ks & 1) a1 = __builtin_amdgcn_mfma_f32_32x32x16_bf16(a, breg[ks], a1, 0, 0, 0);
            else        a0 = __builtin_amdgcn_mfma_f32_32x32x16_bf16(a, breg[ks], a0, 0, 0, 0);
        }
        f32x16 r = a0 + a1;
        float* plw = &pl[t & 1][wave * 32 * PLW];
        #pragma unroll
        for (int ii = 0; ii < 16; ++ii) {
            const int rowc = (ii & 3) + 8 * (ii >> 2) + 4 * (lane >> 5);
            plw[rowc * PLW + word] = r[ii];
        }
        __syncthreads();    // (A) — the ONLY barrier per step

        const float* plr = pl[t & 1];
        float4 h0A = *(const float4*)(plr + ((((mh_e << 1) | 0) * 32 + r_e) * PLW + (jj0 + 0) * 4));
        float4 h0B = *(const float4*)(plr + ((((mh_e << 1) | 1) * 32 + r_e) * PLW + (jj0 + 0) * 4));
        float4 h1A = *(const float4*)(plr + ((((mh_e << 1) | 0) * 32 + r_e) * PLW + (jj0 + 1) * 4));
        float4 h1B = *(const float4*)(plr + ((((mh_e << 1) | 1) * 32 + r_e) * PLW + (jj0 + 1) * 4));
        union { u32x4 u; _Float16 h[8]; } G; G.u = gxv;

        float hv[2];
        {
            const float gF = (float)G.h[0] + h0A.x + h0B.x;
            const float gG = (float)G.h[1] + h0A.y + h0B.y;
            const float gO = (float)G.h[2] + h0A.z + h0B.z;
            const float gR = (float)G.h[3] + h0A.w + h0B.w;
            const float ft = sigf(gF), ot = sigf(gO), rt = sigf(gR);
            const float gt = tanhfast(gG);
            const float cv = ft * creg.x + (1.f - ft) * gt + rt * (float)tm2[0];
            creg.x = cv;
            hv[0] = ot * tanhfast(cv);
        }
        {
            const float gF = (float)G.h[4] + h1A.x + h1B.x;
            const float gG = (float)G.h[5] + h1A.y + h1B.y;
            const float gO = (float)G.h[6] + h1A.z + h1B.z;
            const float gR = (float)G.h[7] + h1A.w + h1B.w;
            const float ft = sigf(gF), ot = sigf(gO), rt = sigf(gR);
            const float gt = tanhfast(gG);
            const float cv = ft * creg.y + (1.f - ft) * gt + rt * (float)tm2[1];
            creg.y = cv;
            hv[1] = ot * tanhfast(cv);
        }
        const unsigned hp2 = (unsigned)f2bf(hv[0]) | ((unsigned)f2bf(hv[1]) << 16);
        __hip_atomic_store((unsigned*)(hseq + (size_t)(t + 1) * BDH + obase), hp2,
                           __ATOMIC_RELAXED, __HIP_MEMORY_SCOPE_AGENT);
        asm volatile("s_waitcnt vmcnt(0)" ::: "memory");   // this wave's h ACKed at LLC
        const unsigned old = __hip_atomic_fetch_add(&hdone, 1u, __ATOMIC_RELAXED,
                                                    __HIP_MEMORY_SCOPE_WORKGROUP);
        if ((old & 3u) == 3u && t < T_STEPS - 1) {         // last wave of this step
            __hip_atomic_store(&gflag[bhh * 128 + js], (unsigned)(t + 1),
                               __ATOMIC_RELAXED, __HIP_MEMORY_SCOPE_AGENT);
        }
        f32x2 hvv = { hv[0], hv[1] };
        __builtin_nontemporal_store(hvv, (f32x2*)(out + (size_t)t * BDH + obase));
    }
}

// ---------------- Tier C fallback: Round-3 persistent kernel ----------------
template<bool XBF16>
__global__ __launch_bounds__(256, 1) void eplstm_persistent(
    const void*  __restrict__ xsrc, const float* __restrict__ mem,
    const float* __restrict__ Wx,   const float* __restrict__ Wh,
    const float* __restrict__ bxp,  const float* __restrict__ bhp,
    const float* __restrict__ c0,
    unsigned short* __restrict__ hseq, float* __restrict__ out,
    unsigned* __restrict__ bar)
{
    extern __shared__ char smem[];
    float* pl = reinterpret_cast<float*>(smem + 131072);

    const int bid = blockIdx.x;
    const int js  = bid >> 1;
    const int bhh = bid & 1;
    const int tid = threadIdx.x;

    {
        const int prow = tid >> 3;
        const int g = prow >> 3, jj = prow & 7;
        const int srow = (g + 1) * 1024 + js * 8 + jj;
        const int kc = (tid & 7) * 256;
        const int sw = (prow & 7) << 4;
        for (int it = 0; it < 32; ++it) {
            const int k = kc + it * 8;
            const float* src = (k < DX) ? (Wx + (size_t)srow * DX + k)
                                        : (Wh + (size_t)srow * DH + (k - DX));
            f32x4v lo = *(const f32x4v*)(src);
            f32x4v hi = *(const f32x4v*)(src + 4);
            short8 v = pack_bf16x8(lo, hi);
            *reinterpret_cast<short8*>(smem + prow * 4096 + ((k * 2) ^ sw)) = v;
        }
    }

    const int e0   = tid * 2;
    const int bl   = e0 >> 3;
    const int jj0  = e0 & 7;
    const int brow_g = bhh * 64 + bl;
    const size_t oidx = (size_t)brow_g * DH + js * 8 + jj0;
    float biasv[2][4];
    #pragma unroll
    for (int e2 = 0; e2 < 2; ++e2)
        #pragma unroll
        for (int g = 0; g < 4; ++g) {
            const int srow = (g + 1) * 1024 + js * 8 + jj0 + e2;
            biasv[e2][g] = bxp[srow] + bhp[srow];
        }
    float2 creg = *reinterpret_cast<const float2*>(c0 + oidx);
    const int mh_e = bl >> 5, rr = bl & 31;

    const int wave = tid >> 6;
    const int lane = tid & 63;
    const int mh = wave >> 1, kh = wave & 1;
    const int arow   = bhh * 64 + mh * 32 + (lane & 31);
    const int k8     = (lane >> 5) * 8;
    const int brow   = lane & 31;
    const char* bbase = smem + brow * 4096;
    const int swz    = (brow & 7) << 4;
    const int kbyte0 = kh * 2048 + k8 * 2;

    __syncthreads();

    for (int t = 0; t < T_STEPS; ++t) {
        f32x16 ac0 = {}, ac1 = {}, ac2 = {}, ac3 = {};
        if (XBF16 || kh == 1) {
            const unsigned short* Ab = kh
                ? (hseq + (size_t)t * BDH + (size_t)arow * DH + k8)
                : ((const unsigned short*)xsrc + (size_t)t * BDX + (size_t)arow * DX + k8);
            #pragma unroll 8
            for (int ks = 0; ks < 64; ++ks) {
                short8 a = *reinterpret_cast<const short8*>(Ab + ks * 16);
                short8 b = *reinterpret_cast<const short8*>(bbase + ((kbyte0 + ks * 32) ^ swz));
                if      ((ks & 3) == 0) ac0 = __builtin_amdgcn_mfma_f32_32x32x16_bf16(a, b, ac0, 0, 0, 0);
                else if ((ks & 3) == 1) ac1 = __builtin_amdgcn_mfma_f32_32x32x16_bf16(a, b, ac1, 0, 0, 0);
                else if ((ks & 3) == 2) ac2 = __builtin_amdgcn_mfma_f32_32x32x16_bf16(a, b, ac2, 0, 0, 0);
                else                    ac3 = __builtin_amdgcn_mfma_f32_32x32x16_bf16(a, b, ac3, 0, 0, 0);
            }
        } else {
            const float* Af = (const float*)xsrc + (size_t)t * BDX + (size_t)arow * DX + k8;
            #pragma unroll 4
            for (int ks = 0; ks < 64; ++ks) {
                f32x4v lo = *(const f32x4v*)(Af + ks * 16);
                f32x4v hi = *(const f32x4v*)(Af + ks * 16 + 4);
                short8 a = pack_bf16x8(lo, hi);
                short8 b = *reinterpret_cast<const short8*>(bbase + ((kbyte0 + ks * 32) ^ swz));
                if      ((ks & 3) == 0) ac0 = __builtin_amdgcn_mfma_f32_32x32x16_bf16(a, b, ac0, 0, 0, 0);
                else if ((ks & 3) == 1) ac1 = __builtin_amdgcn_mfma_f32_32x32x16_bf16(a, b, ac1, 0, 0, 0);
                else if ((ks & 3) == 2) ac2 = __builtin_amdgcn_mfma_f32_32x32x16_bf16(a, b, ac2, 0, 0, 0);
                else                    ac3 = __builtin_amdgcn_mfma_f32_32x32x16_bf16(a, b, ac3, 0, 0, 0);
            }
        }
        f32x16 r = (ac0 + ac1) + (ac2 + ac3);

        #pragma unroll
        for (int i = 0; i < 16; ++i) {
            const int row = (i & 3) + 8 * (i >> 2) + 4 * (lane >> 5);
            pl[(wave * 32 + row) * 33 + brow] = r[i];
        }
        __syncthreads();

        const float2 mt2 = *reinterpret_cast<const float2*>(mem + (size_t)t * BDH + oidx);
        float hv[2];
        #pragma unroll
        for (int e2 = 0; e2 < 2; ++e2) {
            const int jj = jj0 + e2;
            float gs[4];
            #pragma unroll
            for (int g = 0; g < 4; ++g) {
                const int col = g * 8 + jj;
                gs[g] = pl[((mh_e * 2 + 0) * 32 + rr) * 33 + col]
                      + pl[((mh_e * 2 + 1) * 32 + rr) * 33 + col]
                      + biasv[e2][g];
            }
            const float ft = 1.f / (1.f + expf(-gs[0]));
            const float gt = tanhf(gs[1]);
            const float ot = 1.f / (1.f + expf(-gs[2]));
            const float rt = 1.f / (1.f + expf(-gs[3]));
            const float cin = e2 ? creg.y : creg.x;
            const float mvv = e2 ? mt2.y : mt2.x;
            const float cv = ft * cin + (1.f - ft) * gt + rt * tanhf(mvv);
            if (e2) creg.y = cv; else creg.x = cv;
            hv[e2] = ot * tanhf(cv);
        }
        *reinterpret_cast<float2*>(out + (size_t)t * BDH + oidx) = make_float2(hv[0], hv[1]);
        const unsigned hpk = (unsigned)f2bf(hv[0]) | ((unsigned)f2bf(hv[1]) << 16);
        __hip_atomic_store((unsigned*)(hseq + (size_t)(t + 1) * BDH + oidx), hpk,
                           __ATOMIC_RELAXED, __HIP_MEMORY_SCOPE_AGENT);

        __syncthreads();
        if (t < T_STEPS - 1) {
            if (tid == 0) {
                const unsigned want = (unsigned)(t + 1);
                const unsigned arrived = __hip_atomic_fetch_add(
                    &bar[bhh * 32], 1u, __ATOMIC_RELAXED, __HIP_MEMORY_SCOPE_AGENT);
                if (arrived == want * 128u - 1u) {
                    __hip_atomic_store(&bar[64 + bhh * 32], want,
                                       __ATOMIC_RELAXED, __HIP_MEMORY_SCOPE_AGENT);
                } else {
                    while (__hip_atomic_load(&bar[64 + bhh * 32],
                                             __ATOMIC_RELAXED, __HIP_MEMORY_SCOPE_AGENT) < want)
                        __builtin_amdgcn_s_sleep(2);
                }
            }
            __syncthreads();
        }
    }
}

extern "C" void kernel_launch(void* const* d_in, const int* in_sizes, int n_in,
                              void* d_out, int out_size, void* d_ws, size_t ws_size,
                              hipStream_t stream) {
    const float* inputs   = (const float*)d_in[0];
    const float* memories = (const float*)d_in[1];
    const float* h0       = (const float*)d_in[2];
    const float* c0       = (const float*)d_in[3];
    const float* Wx       = (const float*)d_in[4];
    const float* bx       = (const float*)d_in[5];
    const float* Wh       = (const float*)d_in[6];
    const float* bh_      = (const float*)d_in[7];
    float* outp = (float*)d_out;

    char* ws = (char*)d_ws;
    size_t off = 0;
    auto alloc = [&](size_t bytes) {
        char* p = ws + off;
        off = (off + bytes + 255) & ~(size_t)255;
        return p;
    };
    unsigned*       gflag = (unsigned*)alloc(512 * sizeof(unsigned));
    unsigned short* hseq  = (unsigned short*)alloc((size_t)(T_STEPS + 1) * BDH * 2);

    const size_t xb_b = (size_t)T_STEPS * BDX * 2;
    const size_t tm_b = (size_t)T_STEPS * BDH * 2;
    const size_t gx_b = (size_t)16384 * 4096 * 2;
    const size_t need_b = off + xb_b + 256 + tm_b + 256 + gx_b + 256;

    if (ws_size >= need_b) {
        // ---------------- Tier B: prepass + 1-barrier recurrence ----------------
        unsigned short* Xb = (unsigned short*)alloc(xb_b);
        _Float16*       TM = (_Float16*)alloc(tm_b);
        _Float16*       Gx = (_Float16*)alloc(gx_b);

        init_seed<<<512, 256, 0, stream>>>(h0, hseq, gflag);
        prep_x<<<8192, 256, 0, stream>>>(inputs, Xb);
        prep_tm<<<8192, 256, 0, stream>>>(memories, TM);

        const unsigned pre_smem = 131072 + 128 * 72 * 2;     // 149504
        (void)hipFuncSetAttribute((const void*)gx_prepass4,
                                  hipFuncAttributeMaxDynamicSharedMemorySize, pre_smem);
        gx_prepass4<<<512, 256, pre_smem, stream>>>(Xb, Wx, bx, bh_, Gx);

        void* kargs[] = { (void*)&Gx, (void*)&TM, (void*)&Wh, (void*)&c0,
                          (void*)&hseq, (void*)&outp, (void*)&gflag };
        hipError_t err = hipLaunchCooperativeKernel((const void*)eplstm_h, dim3(256),
                                                    dim3(256), kargs, 0, stream);
        if (err != hipSuccess) {
            eplstm_h<<<256, 256, 0, stream>>>(Gx, TM, Wh, c0, hseq, outp, gflag);
        }
    } else {
        // ---------------- Tier C: Round-3 path ----------------
        const bool use_xb = (ws_size >= off + xb_b + 256);
        unsigned short* Xb = use_xb ? (unsigned short*)alloc(xb_b) : nullptr;

        init_seed<<<512, 256, 0, stream>>>(h0, hseq, gflag);
        if (use_xb) prep_x<<<8192, 256, 0, stream>>>(inputs, Xb);

        const unsigned smem_bytes = 131072 + 9216 + 9216 + 64;
        const void* xsrc = use_xb ? (const void*)Xb : (const void*)inputs;
        if (use_xb) {
            (void)hipFuncSetAttribute((const void*)eplstm_persistent<true>,
                                      hipFuncAttributeMaxDynamicSharedMemorySize, smem_bytes);
            void* kargs[] = { (void*)&xsrc, (void*)&memories, (void*)&Wx, (void*)&Wh,
                              (void*)&bx, (void*)&bh_, (void*)&c0, (void*)&hseq,
                              (void*)&outp, (void*)&gflag };
            hipError_t err = hipLaunchCooperativeKernel(
                (const void*)eplstm_persistent<true>, dim3(256), dim3(256),
                kargs, smem_bytes, stream);
            if (err != hipSuccess) {
                eplstm_persistent<true><<<256, 256, smem_bytes, stream>>>(
                    xsrc, memories, Wx, Wh, bx, bh_, c0, hseq, outp, gflag);
            }
        } else {
            (void)hipFuncSetAttribute((const void*)eplstm_persistent<false>,
                                      hipFuncAttributeMaxDynamicSharedMemorySize, smem_bytes);
            void* kargs[] = { (void*)&xsrc, (void*)&memories, (void*)&Wx, (void*)&Wh,
                              (void*)&bx, (void*)&bh_, (void*)&c0, (void*)&hseq,
                              (void*)&outp, (void*)&gflag };
            hipError_t err = hipLaunchCooperativeKernel(
                (const void*)eplstm_persistent<false>, dim3(256), dim3(256),
                kargs, smem_bytes, stream);
            if (err != hipSuccess) {
                eplstm_persistent<false><<<256, 256, smem_bytes, stream>>>(
                    xsrc, memories, Wx, Wh, bx, bh_, c0, hseq, outp, gflag);
            }
        }
    }
}

// Round 11
// 1480.930 us; speedup vs baseline: 1.6100x; 1.6100x over previous
//
#include <hip/hip_runtime.h>

#define T_STEPS 128
#define BATCH   128
#define DX      1024
#define DH      1024
#define BDH     (BATCH * DH)   // 131072
#define BDX     (BATCH * DX)
#define PLW     40             // pl row stride (words)

typedef __attribute__((ext_vector_type(8)))  short short8;
typedef __attribute__((ext_vector_type(16))) float f32x16;
typedef __attribute__((ext_vector_type(4)))  float f32x4v;
typedef __attribute__((ext_vector_type(2)))  float f32x2;
typedef __attribute__((ext_vector_type(4)))  unsigned u32x4;
typedef __attribute__((ext_vector_type(2)))  _Float16 f16x2;

static __device__ __forceinline__ unsigned short f2bf(float f) {
    union { float f; unsigned u; } v; v.f = f;
    unsigned r = v.u + 0x7fffu + ((v.u >> 16) & 1u);   // RNE
    return (unsigned short)(r >> 16);
}
static __device__ __forceinline__ short8 pack_bf16x8(f32x4v lo, f32x4v hi) {
    union { unsigned short u[8]; short8 v; } pk;
    pk.u[0]=f2bf(lo[0]); pk.u[1]=f2bf(lo[1]); pk.u[2]=f2bf(lo[2]); pk.u[3]=f2bf(lo[3]);
    pk.u[4]=f2bf(hi[0]); pk.u[5]=f2bf(hi[1]); pk.u[6]=f2bf(hi[2]); pk.u[7]=f2bf(hi[3]);
    return pk.v;
}
static __device__ __forceinline__ float sigf(float x) {
    float u = __expf(-fabsf(x));
    float b = 1.0f / (1.0f + u);
    return x >= 0.0f ? b : 1.0f - b;
}
static __device__ __forceinline__ float tanhfast(float x) {
    float u = __expf(-2.0f * fabsf(x));
    float r = (1.0f - u) / (1.0f + u);
    return x >= 0.0f ? r : -r;
}

// ---------------- prep kernels ----------------

__global__ __launch_bounds__(256) void prep_x(const float* __restrict__ x,
                                              unsigned short* __restrict__ Xb) {
    const size_t i8 = ((size_t)blockIdx.x * 256 + threadIdx.x) * 8;
    f32x4v lo = __builtin_nontemporal_load((const f32x4v*)(x + i8));
    f32x4v hi = __builtin_nontemporal_load((const f32x4v*)(x + i8 + 4));
    short8 v = pack_bf16x8(lo, hi);
    __builtin_nontemporal_store(v, (short8*)(Xb + i8));
}

// TM = tanh(memories), f16
__global__ __launch_bounds__(256) void prep_tm(const float* __restrict__ mem,
                                               _Float16* __restrict__ TM) {
    const size_t i8 = ((size_t)blockIdx.x * 256 + threadIdx.x) * 8;
    f32x4v lo = __builtin_nontemporal_load((const f32x4v*)(mem + i8));
    f32x4v hi = __builtin_nontemporal_load((const f32x4v*)(mem + i8 + 4));
    union { _Float16 h[8]; u32x4 q; } V;
    #pragma unroll
    for (int j = 0; j < 4; ++j) V.h[j]     = (_Float16)tanhfast(lo[j]);
    #pragma unroll
    for (int j = 0; j < 4; ++j) V.h[4 + j] = (_Float16)tanhfast(hi[j]);
    __builtin_nontemporal_store(V.q, (u32x4*)(TM + i8));
}

__global__ __launch_bounds__(256) void init_seed(const float* __restrict__ h0,
                                                 unsigned short* __restrict__ hseq,
                                                 unsigned* __restrict__ gflag) {
    const int i = blockIdx.x * 256 + threadIdx.x;
    if (i < BDH) hseq[i] = f2bf(h0[i]);
    if (blockIdx.x < 2) gflag[blockIdx.x * 256 + threadIdx.x] = 0;
}

// ---------------- Gx prepass (R6 geometry, W staged from f32) ----------------
// Grid 512: c = bid&7 (XCD chunk -> timesteps c*16..+16; per-XCD x slice 4MB
// bf16, L2-resident), jp = bid>>3 (0..63: 64 perm rows). Stage 128KB W slab
// ONCE from Wx f32 (NT), loop 16 timesteps: M=128 x N=64, K=1024; x A-tile
// read once per mt shared by both N-tiles. Gx f16 out (bias folded, NT).
__global__ __launch_bounds__(256, 1) void gx_prepass4(
    const unsigned short* __restrict__ Xb, const float* __restrict__ Wx,
    const float* __restrict__ bx, const float* __restrict__ bh,
    _Float16* __restrict__ Gx)
{
    extern __shared__ char sm[];                  // [0,128K): W slab; then pl16
    _Float16* pl16 = (_Float16*)(sm + 131072);    // [128][72]

    const int bid = blockIdx.x;
    const int c  = bid & 7;
    const int jp = bid >> 3;                      // 0..63
    const int tid = threadIdx.x;

    {   // stage W slab: 64 perm rows [jp*64,+64), f32->bf16, swizzled
        const int row = tid >> 2;                 // 0..63
        const int chunk = tid & 3;                // K quarter (256 elems)
        const int prow = jp * 64 + row;
        const int srow = ((prow >> 3) & 3) * 1024 + 1024   // gate g+1
                       + (prow >> 5) * 8 + (prow & 7);
        const int sw = (row & 7) << 4;
        const float* W = Wx + (size_t)srow * DX + chunk * 256;
        char* dst = sm + row * 2048;
        #pragma unroll
        for (int it = 0; it < 32; ++it) {
            f32x4v lo = __builtin_nontemporal_load((const f32x4v*)(W + it * 8));
            f32x4v hi = __builtin_nontemporal_load((const f32x4v*)(W + it * 8 + 4));
            short8 v = pack_bf16x8(lo, hi);
            *(short8*)(dst + (((chunk * 256 + it * 8) * 2) ^ sw)) = v;
        }
    }

    const int rrow = tid >> 1;
    const int jjb  = (tid & 1) * 4;
    float bias_f[2][16];
    #pragma unroll
    for (int jsl = 0; jsl < 2; ++jsl)
        #pragma unroll
        for (int q = 0; q < 4; ++q)
            #pragma unroll
            for (int g = 0; g < 4; ++g) {
                const int srow = (g + 1) * 1024 + (jp * 2 + jsl) * 8 + (jjb + q);
                bias_f[jsl][q * 4 + g] = bx[srow] + bh[srow];
            }

    const int wave = tid >> 6, lane = tid & 63;
    const int k8 = (lane >> 5) * 8;
    const char* wrow0 = sm + (lane & 31) * 2048;
    const char* wrow1 = wrow0 + 32 * 2048;
    const int sw2 = ((lane & 31) & 7) << 4;
    __syncthreads();

    for (int i = 0; i < 16; ++i) {
        const int mt = c * 16 + i;                // timestep
        const int arow = mt * 128 + wave * 32 + (lane & 31);
        f32x16 a00 = {}, a01 = {}, a10 = {}, a11 = {};

        const unsigned short* xp = Xb + (size_t)arow * 1024 + k8;
        #pragma unroll 8
        for (int ks = 0; ks < 64; ++ks) {
            short8 a  = *(const short8*)(xp + ks * 16);      // cached: L2-shared
            short8 b0 = *(const short8*)(wrow0 + ((ks * 32 + k8 * 2) ^ sw2));
            short8 b1 = *(const short8*)(wrow1 + ((ks * 32 + k8 * 2) ^ sw2));
            if (ks & 1) {
                a01 = __builtin_amdgcn_mfma_f32_32x32x16_bf16(a, b0, a01, 0, 0, 0);
                a11 = __builtin_amdgcn_mfma_f32_32x32x16_bf16(a, b1, a11, 0, 0, 0);
            } else {
                a00 = __builtin_amdgcn_mfma_f32_32x32x16_bf16(a, b0, a00, 0, 0, 0);
                a10 = __builtin_amdgcn_mfma_f32_32x32x16_bf16(a, b1, a10, 0, 0, 0);
            }
        }
        f32x16 r0 = a00 + a01;
        f32x16 r1 = a10 + a11;

        #pragma unroll
        for (int ii = 0; ii < 16; ++ii) {
            const int rowc = (ii & 3) + 8 * (ii >> 2) + 4 * (lane >> 5);
            pl16[(wave * 32 + rowc) * 72 + (lane & 31)]      = (_Float16)r0[ii];
            pl16[(wave * 32 + rowc) * 72 + 32 + (lane & 31)] = (_Float16)r1[ii];
        }
        __syncthreads();   // pl written

        #pragma unroll
        for (int jsl = 0; jsl < 2; ++jsl) {
            union { _Float16 h[16]; u32x4 q[2]; } V;
            #pragma unroll
            for (int q = 0; q < 4; ++q)
                #pragma unroll
                for (int g = 0; g < 4; ++g)
                    V.h[q * 4 + g] = (_Float16)(
                        (float)pl16[rrow * 72 + jsl * 32 + g * 8 + (jjb + q)]
                        + bias_f[jsl][q * 4 + g]);
            _Float16* dst = Gx + ((size_t)(mt * 128 + rrow) * 4096
                                  + (jp * 2 + jsl) * 32 + jjb * 4);
            __builtin_nontemporal_store(V.q[0], (u32x4*)dst);
            __builtin_nontemporal_store(V.q[1], (u32x4*)(dst + 8));
        }
        __syncthreads();   // pl consumed before next mt overwrites
    }
}

// ---------------- persistent h-recurrence kernel (R8 structure, verbatim) ----------------
// 256 WGs (1/CU). bhh-clustered XCD map: js=(bid>>3)*4+(bid&3), bhh=(bid>>2)&1.
// Wh B-frags in 128 VGPRs. Per step: NT-prefetch Gx/TM -> wave0-only u64 poll
// + barrier(P) [the barrier is the ordering fence: h reads CANNOT hoist above
// it — R10's fence-free variant raced] -> h-GEMM -> pl write -> barrier(A) ->
// epilogue -> h sc1 store -> vmcnt(0) -> barrier(B) -> tid0 flag (RELAXED:
// release would emit buffer_wbl2, the R5 regression) -> NT out store.
__global__ __launch_bounds__(256, 1) void eplstm_h(
    const _Float16* __restrict__ Gx,  const _Float16* __restrict__ TM,
    const float* __restrict__ Wh,     const float* __restrict__ c0,
    unsigned short* __restrict__ hseq, float* __restrict__ out,
    unsigned* __restrict__ gflag)
{
    __shared__ float pl[4 * 32 * PLW];             // 20 KiB

    const int bid = blockIdx.x;
    const int js  = (bid >> 3) * 4 + (bid & 3);    // 0..127
    const int bhh = (bid >> 2) & 1;
    const int tid = threadIdx.x;

    const int wave = tid >> 6, lane = tid & 63;
    const int mh = wave >> 1, kh = wave & 1;
    const int arow = bhh * 64 + mh * 32 + (lane & 31);
    const int k8 = (lane >> 5) * 8;
    const int p = lane & 31;
    const int word = (p & 7) * 4 + (p >> 3);       // jj*4 + g
    float* plw = pl + wave * 32 * PLW;
    unsigned long long* fb = (unsigned long long*)(gflag + bhh * 128);

    // ---- stage this lane's 32 Wh B-fragments into registers (one-time) ----
    short8 breg[32];
    {
        const int r = lane & 31;
        const int g = r >> 3, jj = r & 7;
        const float* Wrow = Wh + (size_t)((g + 1) * 1024 + js * 8 + jj) * 1024
                          + kh * 512 + k8;
        #pragma unroll
        for (int ks = 0; ks < 32; ++ks) {
            f32x4v lo = *(const f32x4v*)(Wrow + ks * 16);
            f32x4v hi = *(const f32x4v*)(Wrow + ks * 16 + 4);
            breg[ks] = pack_bf16x8(lo, hi);
        }
    }

    // epilogue constants (2 outputs/thread)
    const int e0 = tid * 2;
    const int row_e = e0 >> 3;                     // 0..63
    const int jj0 = e0 & 7;                        // even
    const int brow = bhh * 64 + row_e;
    const size_t obase = (size_t)brow * DH + js * 8 + jj0;
    const int mh_e = row_e >> 5, r_e = row_e & 31;
    float2 creg = *(const float2*)(c0 + obase);

    for (int t = 0; t < T_STEPS; ++t) {
        // prefetch h-independent operands BEFORE the wait (NT: single-touch)
        u32x4 gxv = __builtin_nontemporal_load(
            (const u32x4*)(Gx + ((size_t)(t * BATCH + brow) * 4096 + js * 32 + jj0 * 4)));
        f16x2 tm2 = __builtin_nontemporal_load(
            (const f16x2*)(TM + (size_t)t * BDH + obase));

        if (t > 0) {
            if (wave == 0) {     // only wave0 polls LLC; others park in barrier
                for (;;) {
                    unsigned long long fv = __hip_atomic_load(
                        &fb[lane], __ATOMIC_RELAXED, __HIP_MEMORY_SCOPE_AGENT);
                    if (__all(((unsigned)fv >= (unsigned)t) &&
                              ((unsigned)(fv >> 32) >= (unsigned)t))) break;
                    __builtin_amdgcn_s_sleep(2);
                }
            }
            __syncthreads();     // (P) ordering fence + release compute waves
        }

        const unsigned short* hp = hseq + (size_t)t * BDH + (size_t)arow * DH + kh * 512 + k8;
        f32x16 a0 = {}, a1 = {};
        #pragma unroll
        for (int ks = 0; ks < 32; ++ks) {
            short8 a = *(const short8*)(hp + ks * 16);
            if (ks & 1) a1 = __builtin_amdgcn_mfma_f32_32x32x16_bf16(a, breg[ks], a1, 0, 0, 0);
            else        a0 = __builtin_amdgcn_mfma_f32_32x32x16_bf16(a, breg[ks], a0, 0, 0, 0);
        }
        f32x16 r = a0 + a1;
        #pragma unroll
        for (int ii = 0; ii < 16; ++ii) {
            const int rowc = (ii & 3) + 8 * (ii >> 2) + 4 * (lane >> 5);
            plw[rowc * PLW + word] = r[ii];
        }
        __syncthreads();    // (A) partials visible

        float4 h0A = *(const float4*)(pl + ((((mh_e << 1) | 0) * 32 + r_e) * PLW + (jj0 + 0) * 4));
        float4 h0B = *(const float4*)(pl + ((((mh_e << 1) | 1) * 32 + r_e) * PLW + (jj0 + 0) * 4));
        float4 h1A = *(const float4*)(pl + ((((mh_e << 1) | 0) * 32 + r_e) * PLW + (jj0 + 1) * 4));
        float4 h1B = *(const float4*)(pl + ((((mh_e << 1) | 1) * 32 + r_e) * PLW + (jj0 + 1) * 4));
        union { u32x4 u; _Float16 h[8]; } G; G.u = gxv;

        float hv[2];
        {
            const float gF = (float)G.h[0] + h0A.x + h0B.x;
            const float gG = (float)G.h[1] + h0A.y + h0B.y;
            const float gO = (float)G.h[2] + h0A.z + h0B.z;
            const float gR = (float)G.h[3] + h0A.w + h0B.w;
            const float ft = sigf(gF), ot = sigf(gO), rt = sigf(gR);
            const float gt = tanhfast(gG);
            const float cv = ft * creg.x + (1.f - ft) * gt + rt * (float)tm2[0];
            creg.x = cv;
            hv[0] = ot * tanhfast(cv);
        }
        {
            const float gF = (float)G.h[4] + h1A.x + h1B.x;
            const float gG = (float)G.h[5] + h1A.y + h1B.y;
            const float gO = (float)G.h[6] + h1A.z + h1B.z;
            const float gR = (float)G.h[7] + h1A.w + h1B.w;
            const float ft = sigf(gF), ot = sigf(gO), rt = sigf(gR);
            const float gt = tanhfast(gG);
            const float cv = ft * creg.y + (1.f - ft) * gt + rt * (float)tm2[1];
            creg.y = cv;
            hv[1] = ot * tanhfast(cv);
        }
        // h sc1 store, drain ONLY it, then flag; out store leaves critical path
        const unsigned hp2 = (unsigned)f2bf(hv[0]) | ((unsigned)f2bf(hv[1]) << 16);
        __hip_atomic_store((unsigned*)(hseq + (size_t)(t + 1) * BDH + obase), hp2,
                           __ATOMIC_RELAXED, __HIP_MEMORY_SCOPE_AGENT);
        asm volatile("s_waitcnt vmcnt(0)" ::: "memory");   // h stores ACKed at LLC
        __syncthreads();    // (B) all waves drained; pl reusable
        if (tid == 0 && t < T_STEPS - 1) {
            __hip_atomic_store(&gflag[bhh * 128 + js], (unsigned)(t + 1),
                               __ATOMIC_RELAXED, __HIP_MEMORY_SCOPE_AGENT);
        }
        f32x2 hvv = { hv[0], hv[1] };
        __builtin_nontemporal_store(hvv, (f32x2*)(out + (size_t)t * BDH + obase));
    }
}

// ---------------- Tier C fallback: Round-3 persistent kernel ----------------
template<bool XBF16>
__global__ __launch_bounds__(256, 1) void eplstm_persistent(
    const void*  __restrict__ xsrc, const float* __restrict__ mem,
    const float* __restrict__ Wx,   const float* __restrict__ Wh,
    const float* __restrict__ bxp,  const float* __restrict__ bhp,
    const float* __restrict__ c0,
    unsigned short* __restrict__ hseq, float* __restrict__ out,
    unsigned* __restrict__ bar)
{
    extern __shared__ char smem[];
    float* pl = reinterpret_cast<float*>(smem + 131072);

    const int bid = blockIdx.x;
    const int js  = bid >> 1;
    const int bhh = bid & 1;
    const int tid = threadIdx.x;

    {
        const int prow = tid >> 3;
        const int g = prow >> 3, jj = prow & 7;
        const int srow = (g + 1) * 1024 + js * 8 + jj;
        const int kc = (tid & 7) * 256;
        const int sw = (prow & 7) << 4;
        for (int it = 0; it < 32; ++it) {
            const int k = kc + it * 8;
            const float* src = (k < DX) ? (Wx + (size_t)srow * DX + k)
                                        : (Wh + (size_t)srow * DH + (k - DX));
            f32x4v lo = *(const f32x4v*)(src);
            f32x4v hi = *(const f32x4v*)(src + 4);
            short8 v = pack_bf16x8(lo, hi);
            *reinterpret_cast<short8*>(smem + prow * 4096 + ((k * 2) ^ sw)) = v;
        }
    }

    const int e0   = tid * 2;
    const int bl   = e0 >> 3;
    const int jj0  = e0 & 7;
    const int brow_g = bhh * 64 + bl;
    const size_t oidx = (size_t)brow_g * DH + js * 8 + jj0;
    float biasv[2][4];
    #pragma unroll
    for (int e2 = 0; e2 < 2; ++e2)
        #pragma unroll
        for (int g = 0; g < 4; ++g) {
            const int srow = (g + 1) * 1024 + js * 8 + jj0 + e2;
            biasv[e2][g] = bxp[srow] + bhp[srow];
        }
    float2 creg = *reinterpret_cast<const float2*>(c0 + oidx);
    const int mh_e = bl >> 5, rr = bl & 31;

    const int wave = tid >> 6;
    const int lane = tid & 63;
    const int mh = wave >> 1, kh = wave & 1;
    const int arow   = bhh * 64 + mh * 32 + (lane & 31);
    const int k8     = (lane >> 5) * 8;
    const int brow   = lane & 31;
    const char* bbase = smem + brow * 4096;
    const int swz    = (brow & 7) << 4;
    const int kbyte0 = kh * 2048 + k8 * 2;

    __syncthreads();

    for (int t = 0; t < T_STEPS; ++t) {
        f32x16 ac0 = {}, ac1 = {}, ac2 = {}, ac3 = {};
        if (XBF16 || kh == 1) {
            const unsigned short* Ab = kh
                ? (hseq + (size_t)t * BDH + (size_t)arow * DH + k8)
                : ((const unsigned short*)xsrc + (size_t)t * BDX + (size_t)arow * DX + k8);
            #pragma unroll 8
            for (int ks = 0; ks < 64; ++ks) {
                short8 a = *reinterpret_cast<const short8*>(Ab + ks * 16);
                short8 b = *reinterpret_cast<const short8*>(bbase + ((kbyte0 + ks * 32) ^ swz));
                if      ((ks & 3) == 0) ac0 = __builtin_amdgcn_mfma_f32_32x32x16_bf16(a, b, ac0, 0, 0, 0);
                else if ((ks & 3) == 1) ac1 = __builtin_amdgcn_mfma_f32_32x32x16_bf16(a, b, ac1, 0, 0, 0);
                else if ((ks & 3) == 2) ac2 = __builtin_amdgcn_mfma_f32_32x32x16_bf16(a, b, ac2, 0, 0, 0);
                else                    ac3 = __builtin_amdgcn_mfma_f32_32x32x16_bf16(a, b, ac3, 0, 0, 0);
            }
        } else {
            const float* Af = (const float*)xsrc + (size_t)t * BDX + (size_t)arow * DX + k8;
            #pragma unroll 4
            for (int ks = 0; ks < 64; ++ks) {
                f32x4v lo = *(const f32x4v*)(Af + ks * 16);
                f32x4v hi = *(const f32x4v*)(Af + ks * 16 + 4);
                short8 a = pack_bf16x8(lo, hi);
                short8 b = *reinterpret_cast<const short8*>(bbase + ((kbyte0 + ks * 32) ^ swz));
                if      ((ks & 3) == 0) ac0 = __builtin_amdgcn_mfma_f32_32x32x16_bf16(a, b, ac0, 0, 0, 0);
                else if ((ks & 3) == 1) ac1 = __builtin_amdgcn_mfma_f32_32x32x16_bf16(a, b, ac1, 0, 0, 0);
                else if ((ks & 3) == 2) ac2 = __builtin_amdgcn_mfma_f32_32x32x16_bf16(a, b, ac2, 0, 0, 0);
                else                    ac3 = __builtin_amdgcn_mfma_f32_32x32x16_bf16(a, b, ac3, 0, 0, 0);
            }
        }
        f32x16 r = (ac0 + ac1) + (ac2 + ac3);

        #pragma unroll
        for (int i = 0; i < 16; ++i) {
            const int row = (i & 3) + 8 * (i >> 2) + 4 * (lane >> 5);
            pl[(wave * 32 + row) * 33 + brow] = r[i];
        }
        __syncthreads();

        const float2 mt2 = *reinterpret_cast<const float2*>(mem + (size_t)t * BDH + oidx);
        float hv[2];
        #pragma unroll
        for (int e2 = 0; e2 < 2; ++e2) {
            const int jj = jj0 + e2;
            float gs[4];
            #pragma unroll
            for (int g = 0; g < 4; ++g) {
                const int col = g * 8 + jj;
                gs[g] = pl[((mh_e * 2 + 0) * 32 + rr) * 33 + col]
                      + pl[((mh_e * 2 + 1) * 32 + rr) * 33 + col]
                      + biasv[e2][g];
            }
            const float ft = 1.f / (1.f + expf(-gs[0]));
            const float gt = tanhf(gs[1]);
            const float ot = 1.f / (1.f + expf(-gs[2]));
            const float rt = 1.f / (1.f + expf(-gs[3]));
            const float cin = e2 ? creg.y : creg.x;
            const float mvv = e2 ? mt2.y : mt2.x;
            const float cv = ft * cin + (1.f - ft) * gt + rt * tanhf(mvv);
            if (e2) creg.y = cv; else creg.x = cv;
            hv[e2] = ot * tanhf(cv);
        }
        *reinterpret_cast<float2*>(out + (size_t)t * BDH + oidx) = make_float2(hv[0], hv[1]);
        const unsigned hpk = (unsigned)f2bf(hv[0]) | ((unsigned)f2bf(hv[1]) << 16);
        __hip_atomic_store((unsigned*)(hseq + (size_t)(t + 1) * BDH + oidx), hpk,
                           __ATOMIC_RELAXED, __HIP_MEMORY_SCOPE_AGENT);

        __syncthreads();
        if (t < T_STEPS - 1) {
            if (tid == 0) {
                const unsigned want = (unsigned)(t + 1);
                const unsigned arrived = __hip_atomic_fetch_add(
                    &bar[bhh * 32], 1u, __ATOMIC_RELAXED, __HIP_MEMORY_SCOPE_AGENT);
                if (arrived == want * 128u - 1u) {
                    __hip_atomic_store(&bar[64 + bhh * 32], want,
                                       __ATOMIC_RELAXED, __HIP_MEMORY_SCOPE_AGENT);
                } else {
                    while (__hip_atomic_load(&bar[64 + bhh * 32],
                                             __ATOMIC_RELAXED, __HIP_MEMORY_SCOPE_AGENT) < want)
                        __builtin_amdgcn_s_sleep(2);
                }
            }
            __syncthreads();
        }
    }
}

extern "C" void kernel_launch(void* const* d_in, const int* in_sizes, int n_in,
                              void* d_out, int out_size, void* d_ws, size_t ws_size,
                              hipStream_t stream) {
    const float* inputs   = (const float*)d_in[0];
    const float* memories = (const float*)d_in[1];
    const float* h0       = (const float*)d_in[2];
    const float* c0       = (const float*)d_in[3];
    const float* Wx       = (const float*)d_in[4];
    const float* bx       = (const float*)d_in[5];
    const float* Wh       = (const float*)d_in[6];
    const float* bh_      = (const float*)d_in[7];
    float* outp = (float*)d_out;

    char* ws = (char*)d_ws;
    size_t off = 0;
    auto alloc = [&](size_t bytes) {
        char* p = ws + off;
        off = (off + bytes + 255) & ~(size_t)255;
        return p;
    };
    unsigned*       gflag = (unsigned*)alloc(512 * sizeof(unsigned));
    unsigned short* hseq  = (unsigned short*)alloc((size_t)(T_STEPS + 1) * BDH * 2);

    const size_t xb_b = (size_t)T_STEPS * BDX * 2;
    const size_t tm_b = (size_t)T_STEPS * BDH * 2;
    const size_t gx_b = (size_t)16384 * 4096 * 2;
    const size_t need_b = off + xb_b + 256 + tm_b + 256 + gx_b + 256;

    if (ws_size >= need_b) {
        // ---------------- Tier B: prepass4 + R8 recurrence ----------------
        unsigned short* Xb = (unsigned short*)alloc(xb_b);
        _Float16*       TM = (_Float16*)alloc(tm_b);
        _Float16*       Gx = (_Float16*)alloc(gx_b);

        init_seed<<<512, 256, 0, stream>>>(h0, hseq, gflag);
        prep_x<<<8192, 256, 0, stream>>>(inputs, Xb);
        prep_tm<<<8192, 256, 0, stream>>>(memories, TM);

        const unsigned pre_smem = 131072 + 128 * 72 * 2;     // 149504
        (void)hipFuncSetAttribute((const void*)gx_prepass4,
                                  hipFuncAttributeMaxDynamicSharedMemorySize, pre_smem);
        gx_prepass4<<<512, 256, pre_smem, stream>>>(Xb, Wx, bx, bh_, Gx);

        void* kargs[] = { (void*)&Gx, (void*)&TM, (void*)&Wh, (void*)&c0,
                          (void*)&hseq, (void*)&outp, (void*)&gflag };
        hipError_t err = hipLaunchCooperativeKernel((const void*)eplstm_h, dim3(256),
                                                    dim3(256), kargs, 0, stream);
        if (err != hipSuccess) {
            eplstm_h<<<256, 256, 0, stream>>>(Gx, TM, Wh, c0, hseq, outp, gflag);
        }
    } else {
        // ---------------- Tier C: Round-3 path ----------------
        const bool use_xb = (ws_size >= off + xb_b + 256);
        unsigned short* Xb = use_xb ? (unsigned short*)alloc(xb_b) : nullptr;

        init_seed<<<512, 256, 0, stream>>>(h0, hseq, gflag);
        if (use_xb) prep_x<<<8192, 256, 0, stream>>>(inputs, Xb);

        const unsigned smem_bytes = 131072 + 9216 + 9216 + 64;
        const void* xsrc = use_xb ? (const void*)Xb : (const void*)inputs;
        if (use_xb) {
            (void)hipFuncSetAttribute((const void*)eplstm_persistent<true>,
                                      hipFuncAttributeMaxDynamicSharedMemorySize, smem_bytes);
            void* kargs[] = { (void*)&xsrc, (void*)&memories, (void*)&Wx, (void*)&Wh,
                              (void*)&bx, (void*)&bh_, (void*)&c0, (void*)&hseq,
                              (void*)&outp, (void*)&gflag };
            hipError_t err = hipLaunchCooperativeKernel(
                (const void*)eplstm_persistent<true>, dim3(256), dim3(256),
                kargs, smem_bytes, stream);
            if (err != hipSuccess) {
                eplstm_persistent<true><<<256, 256, smem_bytes, stream>>>(
                    xsrc, memories, Wx, Wh, bx, bh_, c0, hseq, outp, gflag);
            }
        } else {
            (void)hipFuncSetAttribute((const void*)eplstm_persistent<false>,
                                      hipFuncAttributeMaxDynamicSharedMemorySize, smem_bytes);
            void* kargs[] = { (void*)&xsrc, (void*)&memories, (void*)&Wx, (void*)&Wh,
                              (void*)&bx, (void*)&bh_, (void*)&c0, (void*)&hseq,
                              (void*)&outp, (void*)&gflag };
            hipError_t err = hipLaunchCooperativeKernel(
                (const void*)eplstm_persistent<false>, dim3(256), dim3(256),
                kargs, smem_bytes, stream);
            if (err != hipSuccess) {
                eplstm_persistent<false><<<256, 256, smem_bytes, stream>>>(
                    xsrc, memories, Wx, Wh, bx, bh_, c0, hseq, outp, gflag);
            }
        }
    }
}